// Round 6
// baseline (280.723 us; speedup 1.0000x reference)
//
#include <hip/hip_runtime.h>

#define WS_ALIGN(x) (((x) + size_t(255)) & ~size_t(255))

// Phase A: partition edges into 8 col-range buckets. Pack (row,col) into one
// uint: row<2^17 in bits [31:14], (col - bucket_lo)<12500 in bits [13:0].
// Allocation: per-wave LDS histograms -> ONE padded global atomicAdd per
// bucket per block. NO deg atomics here (they caused 50MB of line bouncing).
__global__ __launch_bounds__(256) void k_bucket(const int* __restrict__ row,
                                                const int* __restrict__ col,
                                                int* __restrict__ bcur,   // stride 16 ints (64B)
                                                unsigned int* __restrict__ pairs,
                                                int E, unsigned int magic, int npg, int cap) {
    __shared__ int lcnt[4][8];
    __shared__ int wbase[4][8];
    int wid = threadIdx.x >> 6;
    if (threadIdx.x < 32) lcnt[threadIdx.x >> 3][threadIdx.x & 7] = 0;
    __syncthreads();

    int t0 = blockIdx.x * 2048;
    int b[8], rk[8];
    unsigned int pk[8];
#pragma unroll
    for (int k = 0; k < 8; k++) {
        int e = t0 + k * 256 + threadIdx.x;
        b[k] = -1;
        if (e < E) {
            int r = row[e], c = col[e];
            int bb = (int)(((unsigned long long)(unsigned)c * magic) >> 44);  // c/npg
            b[k] = bb;
            pk[k] = ((unsigned)r << 14) | (unsigned)(c - bb * npg);
            rk[k] = atomicAdd(&lcnt[wid][bb], 1);
        }
    }
    __syncthreads();
    if (threadIdx.x < 8) {
        int bb = threadIdx.x;
        int c0 = lcnt[0][bb], c1 = lcnt[1][bb], c2 = lcnt[2][bb], c3 = lcnt[3][bb];
        int tot = (c0 + c1) + (c2 + c3);
        int base = tot ? atomicAdd(&bcur[bb * 16], tot) : 0;
        wbase[0][bb] = base;
        wbase[1][bb] = base + c0;
        wbase[2][bb] = base + c0 + c1;
        wbase[3][bb] = base + c0 + c1 + c2;
    }
    __syncthreads();
#pragma unroll
    for (int k = 0; k < 8; k++) {
        if (b[k] >= 0)
            pairs[(size_t)b[k] * cap + wbase[wid][b[k]] + rk[k]] = pk[k];
    }
}

// Phase B: per-bucket degree count. Bucket b's blocks (blockIdx&7) atomically
// bump deg in the bucket's OWN 50KB window -> no cross-XCD line bouncing;
// pair slice is L2/L3-resident from phase A.
__global__ __launch_bounds__(256) void k_count2(const unsigned int* __restrict__ pairs,
                                                const int* __restrict__ bcur,
                                                int* __restrict__ deg, int npg, int cap) {
    int b = blockIdx.x & 7;
    int j = blockIdx.x >> 3;
    int nblk = gridDim.x >> 3;
    int cnt = bcur[b * 16];
    int lo = b * npg;
    const unsigned int* p = pairs + (size_t)b * cap;
    for (int i = j * 256 + threadIdx.x; i < cnt; i += nblk * 256)
        atomicAdd(&deg[lo + (int)(p[i] & 16383u)], 1);
}

// per-block inclusive scan of deg -> offs1 (= offsets+1), block totals -> bsums
__global__ __launch_bounds__(1024) void k_scan_blocks(const int* deg, int* offs1, int* bsums, int n) {
    __shared__ int s[1024];
    int gid = blockIdx.x * 1024 + threadIdx.x;
    int v = (gid < n) ? deg[gid] : 0;
    s[threadIdx.x] = v;
    __syncthreads();
    for (int d = 1; d < 1024; d <<= 1) {
        int t = (threadIdx.x >= (unsigned)d) ? s[threadIdx.x - d] : 0;
        __syncthreads();
        s[threadIdx.x] += t;
        __syncthreads();
    }
    if (gid < n) offs1[gid] = s[threadIdx.x];
    if (threadIdx.x == 1023) bsums[blockIdx.x] = s[1023];
}

__global__ __launch_bounds__(1024) void k_scan_sums(int* bsums, int nb) {
    __shared__ int s[1024];
    int v = (threadIdx.x < (unsigned)nb) ? bsums[threadIdx.x] : 0;
    s[threadIdx.x] = v;
    __syncthreads();
    for (int d = 1; d < 1024; d <<= 1) {
        int t = (threadIdx.x >= (unsigned)d) ? s[threadIdx.x - d] : 0;
        __syncthreads();
        s[threadIdx.x] += t;
        __syncthreads();
    }
    if (threadIdx.x < (unsigned)nb) bsums[threadIdx.x] = s[threadIdx.x] - v; // exclusive
}

// finalize offsets; emit cursor (=offs) and dinv. Race-free: thread gid owns offs[gid+1].
__global__ __launch_bounds__(256) void k_add_offsets(int* __restrict__ offs,
                                                     const int* __restrict__ bsums,
                                                     const int* __restrict__ deg,
                                                     float* __restrict__ dinv,
                                                     int* __restrict__ cursor, int n) {
    int gid = blockIdx.x * 256 + threadIdx.x;
    if (gid >= n) return;
    int val = offs[gid + 1] + bsums[gid >> 10];
    offs[gid + 1] = val;
    cursor[gid + 1] = val;
    if (gid == 0) { offs[0] = 0; cursor[0] = 0; }
    dinv[gid] = rsqrtf((float)(deg[gid] + 1));  // +1 self loop
}

// Phase D: bucket b scatters rows into its adj window. Per-XCD working set:
// ~0.8MB packed pairs + 50KB cursor + 0.8MB adj -> L2-resident.
__global__ __launch_bounds__(256) void k_bin2(const unsigned int* __restrict__ pairs,
                                              const int* __restrict__ bcur,
                                              int* __restrict__ cursor,
                                              int* __restrict__ adj, int npg, int cap) {
    int b = blockIdx.x & 7;
    int j = blockIdx.x >> 3;
    int nblk = gridDim.x >> 3;
    int cnt = bcur[b * 16];
    int lo = b * npg;
    const unsigned int* p = pairs + (size_t)b * cap;
    for (int i = j * 256 + threadIdx.x; i < cnt; i += nblk * 256) {
        unsigned int pk = p[i];
        int pos = atomicAdd(&cursor[lo + (int)(pk & 16383u)], 1);
        adj[pos] = (int)(pk >> 14);
    }
}

// h1s = (x @ W1) * dinv[node]   x:[n,128] W1:[128,64]
__global__ __launch_bounds__(256) void k_gemm1(const float* __restrict__ x,
                                               const float* __restrict__ W1,
                                               const float* __restrict__ dinv,
                                               float* __restrict__ h1s, int n) {
    __shared__ float xs[32][132];
    __shared__ float Ws[128][64];
    int base = blockIdx.x * 32;
    for (int q = threadIdx.x; q < 1024; q += 256) {
        int nd = q >> 5, kf = q & 31;
        int gn = base + nd;
        float4 v = (gn < n) ? *(const float4*)&x[(size_t)gn * 128 + kf * 4]
                            : make_float4(0.f, 0.f, 0.f, 0.f);
        *(float4*)&xs[nd][kf * 4] = v;
    }
    for (int q = threadIdx.x; q < 2048; q += 256) {
        float4 v = ((const float4*)W1)[q];
        int k = q >> 4, cf = q & 15;
        *(float4*)&Ws[k][cf * 4] = v;
    }
    __syncthreads();

    int wid = threadIdx.x >> 6, lane = threadIdx.x & 63;
    int r = (wid << 3) + (lane & 7);
    int cbase = (lane >> 3) << 3;
    float4 a0 = make_float4(0.f, 0.f, 0.f, 0.f);
    float4 a1 = make_float4(0.f, 0.f, 0.f, 0.f);
#pragma unroll 4
    for (int k4 = 0; k4 < 32; k4++) {
        float4 xv = *(const float4*)&xs[r][k4 * 4];
#pragma unroll
        for (int kk = 0; kk < 4; kk++) {
            float xk = (&xv.x)[kk];
            float4 w0 = *(const float4*)&Ws[k4 * 4 + kk][cbase];
            float4 w1 = *(const float4*)&Ws[k4 * 4 + kk][cbase + 4];
            a0.x = fmaf(xk, w0.x, a0.x); a0.y = fmaf(xk, w0.y, a0.y);
            a0.z = fmaf(xk, w0.z, a0.z); a0.w = fmaf(xk, w0.w, a0.w);
            a1.x = fmaf(xk, w1.x, a1.x); a1.y = fmaf(xk, w1.y, a1.y);
            a1.z = fmaf(xk, w1.z, a1.z); a1.w = fmaf(xk, w1.w, a1.w);
        }
    }
    int node = base + r;
    if (node < n) {
        float di = dinv[node];
        a0.x *= di; a0.y *= di; a0.z *= di; a0.w *= di;
        a1.x *= di; a1.y *= di; a1.z *= di; a1.w *= di;
        float* o = &h1s[(size_t)node * 64 + cbase];
        *(float4*)o = a0;
        *(float4*)(o + 4) = a1;
    }
}

// layer-1 aggregation fused with layer-2 GEMM (shuffle reduction)
__global__ __launch_bounds__(256) void k_agg1(const float* __restrict__ h1s,
                                              const float* __restrict__ dinv,
                                              const int* __restrict__ offs,
                                              const int* __restrict__ adj,
                                              const float* __restrict__ b1,
                                              const float* __restrict__ W2,
                                              float* __restrict__ h2s, int n) {
    int wid = threadIdx.x >> 6, lane = threadIdx.x & 63;
    int i = blockIdx.x * 4 + wid;
    if (i >= n) return;
    int s = __builtin_amdgcn_readfirstlane(offs[i]);
    int e = __builtin_amdgcn_readfirstlane(offs[i + 1]);
    float acc0 = 0.f, acc1 = 0.f, acc2 = 0.f, acc3 = 0.f;
    int p = s;
    for (; p + 4 <= e; p += 4) {
        int s0 = adj[p], s1 = adj[p + 1], s2 = adj[p + 2], s3 = adj[p + 3];
        acc0 += h1s[(size_t)s0 * 64 + lane];
        acc1 += h1s[(size_t)s1 * 64 + lane];
        acc2 += h1s[(size_t)s2 * 64 + lane];
        acc3 += h1s[(size_t)s3 * 64 + lane];
    }
    int rem = e - p;
    if (rem > 0) {
        int q0 = adj[p];
        int q1 = (rem > 1) ? adj[p + 1] : q0;
        int q2 = (rem > 2) ? adj[p + 2] : q0;
        float v0 = h1s[(size_t)q0 * 64 + lane];
        float v1 = h1s[(size_t)q1 * 64 + lane];
        float v2 = h1s[(size_t)q2 * 64 + lane];
        acc0 += v0;
        if (rem > 1) acc1 += v1;
        if (rem > 2) acc2 += v2;
    }
    float acc = (acc0 + acc1) + (acc2 + acc3);
    float di = dinv[i];
    float val = fmaf(di, acc + h1s[(size_t)i * 64 + lane], b1[lane]);
    val = fmaxf(val, 0.f);
    float w0 = W2[lane * 2], w1 = W2[lane * 2 + 1];
    float t0 = val * w0, t1 = val * w1;
#pragma unroll
    for (int m = 1; m < 64; m <<= 1) {
        t0 += __shfl_xor(t0, m, 64);
        t1 += __shfl_xor(t1, m, 64);
    }
    if (lane == 0) {
        h2s[(size_t)i * 2]     = t0 * di;
        h2s[(size_t)i * 2 + 1] = t1 * di;
    }
}

// layer-2 aggregation: thread per node; out = di*(sum h2s[src] + h2s[i]) + b2
__global__ __launch_bounds__(256) void k_agg2(const float* __restrict__ h2s,
                                              const float* __restrict__ dinv,
                                              const int* __restrict__ offs,
                                              const int* __restrict__ adj,
                                              const float* __restrict__ b2,
                                              float* __restrict__ out, int n) {
    int i = blockIdx.x * 256 + threadIdx.x;
    if (i >= n) return;
    int s = offs[i], e = offs[i + 1];
    float a0x = 0.f, a0y = 0.f, a1x = 0.f, a1y = 0.f;
    float a2x = 0.f, a2y = 0.f, a3x = 0.f, a3y = 0.f;
    int p = s;
    for (; p + 4 <= e; p += 4) {
        int s0 = adj[p], s1 = adj[p + 1], s2 = adj[p + 2], s3 = adj[p + 3];
        float2 v0 = *(const float2*)(h2s + (size_t)s0 * 2);
        float2 v1 = *(const float2*)(h2s + (size_t)s1 * 2);
        float2 v2 = *(const float2*)(h2s + (size_t)s2 * 2);
        float2 v3 = *(const float2*)(h2s + (size_t)s3 * 2);
        a0x += v0.x; a0y += v0.y;
        a1x += v1.x; a1y += v1.y;
        a2x += v2.x; a2y += v2.y;
        a3x += v3.x; a3y += v3.y;
    }
    int rem = e - p;
    if (rem > 0) {
        int q0 = adj[p];
        int q1 = (rem > 1) ? adj[p + 1] : q0;
        int q2 = (rem > 2) ? adj[p + 2] : q0;
        float2 v0 = *(const float2*)(h2s + (size_t)q0 * 2);
        float2 v1 = *(const float2*)(h2s + (size_t)q1 * 2);
        float2 v2 = *(const float2*)(h2s + (size_t)q2 * 2);
        a0x += v0.x; a0y += v0.y;
        if (rem > 1) { a1x += v1.x; a1y += v1.y; }
        if (rem > 2) { a2x += v2.x; a2y += v2.y; }
    }
    float ax = (a0x + a1x) + (a2x + a3x);
    float ay = (a0y + a1y) + (a2y + a3y);
    float di = dinv[i];
    float2 hv = *(const float2*)(h2s + (size_t)i * 2);
    out[(size_t)i * 2]     = fmaf(di, ax + hv.x, b2[0]);
    out[(size_t)i * 2 + 1] = fmaf(di, ay + hv.y, b2[1]);
}

extern "C" void kernel_launch(void* const* d_in, const int* in_sizes, int n_in,
                              void* d_out, int out_size, void* d_ws, size_t ws_size,
                              hipStream_t stream) {
    const float* x  = (const float*)d_in[0];
    const int*   ei = (const int*)d_in[1];
    const float* W1 = (const float*)d_in[2];
    const float* b1 = (const float*)d_in[3];
    const float* W2 = (const float*)d_in[4];
    const float* b2 = (const float*)d_in[5];
    float* out = (float*)d_out;

    int N = in_sizes[0] / 128;   // 100000
    int E = in_sizes[1] / 2;     // 1600000
    const int* row = ei;
    const int* col = ei + E;

    char* ws = (char*)d_ws;
    size_t off = 0;
    auto alloc = [&](size_t bytes) -> char* {
        char* p = ws + off;
        off = WS_ALIGN(off + bytes);
        return p;
    };
    int*   deg    = (int*)alloc((size_t)N * 4 + 512);   // bcur (8x16 ints) rides after deg
    int*   bcur   = deg + N;                             // padded, zeroed with deg
    int*   offs   = (int*)alloc((size_t)(N + 1) * 4);
    int*   cursor = (int*)alloc((size_t)(N + 1) * 4);
    int*   bsums  = (int*)alloc(4096);
    float* dinv   = (float*)alloc((size_t)N * 4);
    int*   adj    = (int*)alloc((size_t)E * 4);
    float* h1s    = (float*)alloc((size_t)N * 64 * 4);
    float* h2s    = (float*)alloc((size_t)N * 2 * 4);
    unsigned int* pairs = (unsigned int*)h1s;  // alias: dead before gemm1 writes h1s

    int nb  = (N + 1023) / 1024;
    int npg = (N + 7) / 8;                               // 12500
    const int CAP = 262144;                              // per-bucket capacity
    unsigned int magic = (unsigned int)(((1ULL << 44) + (unsigned long long)npg - 1)
                                        / (unsigned long long)npg);

    hipMemsetAsync(deg, 0, (size_t)N * 4 + 512, stream);
    hipLaunchKernelGGL(k_bucket, dim3((E + 2047) / 2048), dim3(256), 0, stream,
                       row, col, bcur, pairs, E, magic, npg, CAP);
    hipLaunchKernelGGL(k_count2, dim3(1024), dim3(256), 0, stream, pairs, bcur, deg, npg, CAP);
    hipLaunchKernelGGL(k_scan_blocks, dim3(nb), dim3(1024), 0, stream, deg, offs + 1, bsums, N);
    hipLaunchKernelGGL(k_scan_sums, dim3(1), dim3(1024), 0, stream, bsums, nb);
    hipLaunchKernelGGL(k_add_offsets, dim3((N + 255) / 256), dim3(256), 0, stream,
                       offs, bsums, deg, dinv, cursor, N);
    hipLaunchKernelGGL(k_bin2, dim3(1024), dim3(256), 0, stream, pairs, bcur, cursor, adj, npg, CAP);
    hipLaunchKernelGGL(k_gemm1, dim3((N + 31) / 32), dim3(256), 0, stream, x, W1, dinv, h1s, N);
    hipLaunchKernelGGL(k_agg1, dim3((N + 3) / 4), dim3(256), 0, stream, h1s, dinv, offs, adj, b1, W2, h2s, N);
    hipLaunchKernelGGL(k_agg2, dim3((N + 255) / 256), dim3(256), 0, stream, h2s, dinv, offs, adj, b2, out, N);
}

// Round 7
// 176.837 us; speedup vs baseline: 1.5875x; 1.5875x over previous
//
#include <hip/hip_runtime.h>

#define WS_ALIGN(x) (((x) + size_t(255)) & ~size_t(255))

// ---- Phase A: partition edges into 8 col-range buckets. Packed edge:
// row (18b) << 14 | local_col (14b, < 12500). Block-tiled LDS histogram ->
// ONE padded global atomicAdd per bucket per block. No per-edge global atomics.
__global__ __launch_bounds__(256) void k_bucket(const int* __restrict__ row,
                                                const int* __restrict__ col,
                                                int* __restrict__ bcur,   // stride 16 ints
                                                unsigned int* __restrict__ pairs,
                                                int E, unsigned int magic, int npg, int cap) {
    __shared__ int lcnt[4][8];
    __shared__ int wbase[4][8];
    int wid = threadIdx.x >> 6;
    if (threadIdx.x < 32) lcnt[threadIdx.x >> 3][threadIdx.x & 7] = 0;
    __syncthreads();

    int t0 = blockIdx.x * 2048;
    int b[8], rk[8];
    unsigned int pk[8];
#pragma unroll
    for (int k = 0; k < 8; k++) {
        int e = t0 + k * 256 + threadIdx.x;
        b[k] = -1;
        if (e < E) {
            int r = row[e], c = col[e];
            int bb = (int)(((unsigned long long)(unsigned)c * magic) >> 44);  // c/npg
            b[k] = bb;
            pk[k] = ((unsigned)r << 14) | (unsigned)(c - bb * npg);
            rk[k] = atomicAdd(&lcnt[wid][bb], 1);
        }
    }
    __syncthreads();
    if (threadIdx.x < 8) {
        int bb = threadIdx.x;
        int c0 = lcnt[0][bb], c1 = lcnt[1][bb], c2 = lcnt[2][bb], c3 = lcnt[3][bb];
        int tot = (c0 + c1) + (c2 + c3);
        int base = tot ? atomicAdd(&bcur[bb * 16], tot) : 0;
        wbase[0][bb] = base;
        wbase[1][bb] = base + c0;
        wbase[2][bb] = base + c0 + c1;
        wbase[3][bb] = base + c0 + c1 + c2;
    }
    __syncthreads();
#pragma unroll
    for (int k = 0; k < 8; k++) {
        if (b[k] >= 0)
            pairs[(size_t)b[k] * cap + wbase[wid][b[k]] + rk[k]] = pk[k];
    }
}

// ---- Phase B: refine bucket b into 49 sub-buckets of 256 cols (lc>>8).
// 4096-edge tiles; per-wave LDS histograms; one padded global atomicAdd per
// sub-bucket per tile (~19k total). Writes ~334B chunks per sub-bucket.
__global__ __launch_bounds__(256) void k_refine(const unsigned int* __restrict__ pairs1,
                                                const int* __restrict__ bcur,
                                                int* __restrict__ bcur2,  // stride 16 ints
                                                unsigned int* __restrict__ pairs2,
                                                int cap1, int cap2) {
    __shared__ int lcnt[4][64];
    __shared__ int wbase[4][64];
    int b = blockIdx.x & 7;
    int j = blockIdx.x >> 3;
    int nblk = gridDim.x >> 3;
    int wid = threadIdx.x >> 6;
    int cnt = bcur[b * 16];
    const unsigned int* src = pairs1 + (size_t)b * cap1;
    unsigned int* dst = pairs2 + (size_t)b * 49 * cap2;
    int* mycur = bcur2 + b * 49 * 16;

    for (int t0 = j * 4096; t0 < cnt; t0 += nblk * 4096) {
        lcnt[threadIdx.x >> 6][threadIdx.x & 63] = 0;
        __syncthreads();
        unsigned int pk[16];
        int sb[16], rk[16];
#pragma unroll
        for (int k = 0; k < 16; k++) {
            int e = t0 + k * 256 + threadIdx.x;
            sb[k] = -1;
            if (e < cnt) {
                pk[k] = src[e];
                sb[k] = (int)((pk[k] & 16383u) >> 8);   // 0..48
                rk[k] = atomicAdd(&lcnt[wid][sb[k]], 1);
            }
        }
        __syncthreads();
        if (threadIdx.x < 64) {
            int s = threadIdx.x;
            int c0 = lcnt[0][s], c1 = lcnt[1][s], c2 = lcnt[2][s], c3 = lcnt[3][s];
            int tot = (c0 + c1) + (c2 + c3);
            int base = tot ? atomicAdd(&mycur[s * 16], tot) : 0;
            wbase[0][s] = base;
            wbase[1][s] = base + c0;
            wbase[2][s] = base + c0 + c1;
            wbase[3][s] = base + c0 + c1 + c2;
        }
        __syncthreads();
#pragma unroll
        for (int k = 0; k < 16; k++) {
            if (sb[k] >= 0)
                dst[(size_t)sb[k] * cap2 + wbase[wid][sb[k]] + rk[k]] = pk[k];
        }
        __syncthreads();
    }
}

// ---- C1: per-sub-bucket degree count via LDS histogram; coalesced deg store.
__global__ __launch_bounds__(256) void k_degcnt(const unsigned int* __restrict__ pairs2,
                                                const int* __restrict__ bcur2,
                                                int* __restrict__ deg, int npg, int cap2) {
    __shared__ int hist[256];
    int sbid = blockIdx.x;
    int b = sbid / 49, s = sbid - b * 49;
    int cnt = bcur2[sbid * 16];
    const unsigned int* src = pairs2 + (size_t)sbid * cap2;
    hist[threadIdx.x] = 0;
    __syncthreads();
    for (int i = threadIdx.x; i < cnt; i += 256)
        atomicAdd(&hist[src[i] & 255u], 1);
    __syncthreads();
    int ncols = min(256, npg - s * 256);
    if (threadIdx.x < ncols)
        deg[b * npg + s * 256 + threadIdx.x] = hist[threadIdx.x];
}

// per-block inclusive scan of deg -> offs1 (= offsets+1), block totals -> bsums
__global__ __launch_bounds__(1024) void k_scan_blocks(const int* deg, int* offs1, int* bsums, int n) {
    __shared__ int s[1024];
    int gid = blockIdx.x * 1024 + threadIdx.x;
    int v = (gid < n) ? deg[gid] : 0;
    s[threadIdx.x] = v;
    __syncthreads();
    for (int d = 1; d < 1024; d <<= 1) {
        int t = (threadIdx.x >= (unsigned)d) ? s[threadIdx.x - d] : 0;
        __syncthreads();
        s[threadIdx.x] += t;
        __syncthreads();
    }
    if (gid < n) offs1[gid] = s[threadIdx.x];
    if (threadIdx.x == 1023) bsums[blockIdx.x] = s[1023];
}

__global__ __launch_bounds__(1024) void k_scan_sums(int* bsums, int nb) {
    __shared__ int s[1024];
    int v = (threadIdx.x < (unsigned)nb) ? bsums[threadIdx.x] : 0;
    s[threadIdx.x] = v;
    __syncthreads();
    for (int d = 1; d < 1024; d <<= 1) {
        int t = (threadIdx.x >= (unsigned)d) ? s[threadIdx.x - d] : 0;
        __syncthreads();
        s[threadIdx.x] += t;
        __syncthreads();
    }
    if (threadIdx.x < (unsigned)nb) bsums[threadIdx.x] = s[threadIdx.x] - v; // exclusive
}

// finalize offsets; emit dinv. Race-free: thread gid owns offs[gid+1].
__global__ __launch_bounds__(256) void k_add_offsets(int* __restrict__ offs,
                                                     const int* __restrict__ bsums,
                                                     const int* __restrict__ deg,
                                                     float* __restrict__ dinv, int n) {
    int gid = blockIdx.x * 256 + threadIdx.x;
    if (gid >= n) return;
    offs[gid + 1] += bsums[gid >> 10];
    if (gid == 0) offs[0] = 0;
    dinv[gid] = rsqrtf((float)(deg[gid] + 1));  // +1 self loop
}

// ---- C2: per-sub-bucket counting-sort scatter into the sub-bucket's
// contiguous adj window. LDS cursors seeded from offs. No global atomics.
__global__ __launch_bounds__(256) void k_binsort(const unsigned int* __restrict__ pairs2,
                                                 const int* __restrict__ bcur2,
                                                 const int* __restrict__ offs,
                                                 int* __restrict__ adj, int npg, int cap2) {
    __shared__ int cur[256];
    int sbid = blockIdx.x;
    int b = sbid / 49, s = sbid - b * 49;
    int cnt = bcur2[sbid * 16];
    const unsigned int* src = pairs2 + (size_t)sbid * cap2;
    int colbase = b * npg + s * 256;
    int ncols = min(256, npg - s * 256);
    if (threadIdx.x < ncols) cur[threadIdx.x] = offs[colbase + threadIdx.x];
    __syncthreads();
    for (int i = threadIdx.x; i < cnt; i += 256) {
        unsigned int pk = src[i];
        int pos = atomicAdd(&cur[pk & 255u], 1);
        adj[pos] = (int)(pk >> 14);
    }
}

// h1s = (x @ W1) * dinv[node]   x:[n,128] W1:[128,64]
__global__ __launch_bounds__(256) void k_gemm1(const float* __restrict__ x,
                                               const float* __restrict__ W1,
                                               const float* __restrict__ dinv,
                                               float* __restrict__ h1s, int n) {
    __shared__ float xs[32][132];
    __shared__ float Ws[128][64];
    int base = blockIdx.x * 32;
    for (int q = threadIdx.x; q < 1024; q += 256) {
        int nd = q >> 5, kf = q & 31;
        int gn = base + nd;
        float4 v = (gn < n) ? *(const float4*)&x[(size_t)gn * 128 + kf * 4]
                            : make_float4(0.f, 0.f, 0.f, 0.f);
        *(float4*)&xs[nd][kf * 4] = v;
    }
    for (int q = threadIdx.x; q < 2048; q += 256) {
        float4 v = ((const float4*)W1)[q];
        int k = q >> 4, cf = q & 15;
        *(float4*)&Ws[k][cf * 4] = v;
    }
    __syncthreads();

    int wid = threadIdx.x >> 6, lane = threadIdx.x & 63;
    int r = (wid << 3) + (lane & 7);
    int cbase = (lane >> 3) << 3;
    float4 a0 = make_float4(0.f, 0.f, 0.f, 0.f);
    float4 a1 = make_float4(0.f, 0.f, 0.f, 0.f);
#pragma unroll 4
    for (int k4 = 0; k4 < 32; k4++) {
        float4 xv = *(const float4*)&xs[r][k4 * 4];
#pragma unroll
        for (int kk = 0; kk < 4; kk++) {
            float xk = (&xv.x)[kk];
            float4 w0 = *(const float4*)&Ws[k4 * 4 + kk][cbase];
            float4 w1 = *(const float4*)&Ws[k4 * 4 + kk][cbase + 4];
            a0.x = fmaf(xk, w0.x, a0.x); a0.y = fmaf(xk, w0.y, a0.y);
            a0.z = fmaf(xk, w0.z, a0.z); a0.w = fmaf(xk, w0.w, a0.w);
            a1.x = fmaf(xk, w1.x, a1.x); a1.y = fmaf(xk, w1.y, a1.y);
            a1.z = fmaf(xk, w1.z, a1.z); a1.w = fmaf(xk, w1.w, a1.w);
        }
    }
    int node = base + r;
    if (node < n) {
        float di = dinv[node];
        a0.x *= di; a0.y *= di; a0.z *= di; a0.w *= di;
        a1.x *= di; a1.y *= di; a1.z *= di; a1.w *= di;
        float* o = &h1s[(size_t)node * 64 + cbase];
        *(float4*)o = a0;
        *(float4*)(o + 4) = a1;
    }
}

// layer-1 aggregation fused with layer-2 GEMM (shuffle reduction)
__global__ __launch_bounds__(256) void k_agg1(const float* __restrict__ h1s,
                                              const float* __restrict__ dinv,
                                              const int* __restrict__ offs,
                                              const int* __restrict__ adj,
                                              const float* __restrict__ b1,
                                              const float* __restrict__ W2,
                                              float* __restrict__ h2s, int n) {
    int wid = threadIdx.x >> 6, lane = threadIdx.x & 63;
    int i = blockIdx.x * 4 + wid;
    if (i >= n) return;
    int s = __builtin_amdgcn_readfirstlane(offs[i]);
    int e = __builtin_amdgcn_readfirstlane(offs[i + 1]);
    float acc0 = 0.f, acc1 = 0.f, acc2 = 0.f, acc3 = 0.f;
    int p = s;
    for (; p + 4 <= e; p += 4) {
        int s0 = adj[p], s1 = adj[p + 1], s2 = adj[p + 2], s3 = adj[p + 3];
        acc0 += h1s[(size_t)s0 * 64 + lane];
        acc1 += h1s[(size_t)s1 * 64 + lane];
        acc2 += h1s[(size_t)s2 * 64 + lane];
        acc3 += h1s[(size_t)s3 * 64 + lane];
    }
    int rem = e - p;
    if (rem > 0) {
        int q0 = adj[p];
        int q1 = (rem > 1) ? adj[p + 1] : q0;
        int q2 = (rem > 2) ? adj[p + 2] : q0;
        float v0 = h1s[(size_t)q0 * 64 + lane];
        float v1 = h1s[(size_t)q1 * 64 + lane];
        float v2 = h1s[(size_t)q2 * 64 + lane];
        acc0 += v0;
        if (rem > 1) acc1 += v1;
        if (rem > 2) acc2 += v2;
    }
    float acc = (acc0 + acc1) + (acc2 + acc3);
    float di = dinv[i];
    float val = fmaf(di, acc + h1s[(size_t)i * 64 + lane], b1[lane]);
    val = fmaxf(val, 0.f);
    float w0 = W2[lane * 2], w1 = W2[lane * 2 + 1];
    float t0 = val * w0, t1 = val * w1;
#pragma unroll
    for (int m = 1; m < 64; m <<= 1) {
        t0 += __shfl_xor(t0, m, 64);
        t1 += __shfl_xor(t1, m, 64);
    }
    if (lane == 0) {
        h2s[(size_t)i * 2]     = t0 * di;
        h2s[(size_t)i * 2 + 1] = t1 * di;
    }
}

// layer-2 aggregation: thread per node; out = di*(sum h2s[src] + h2s[i]) + b2
__global__ __launch_bounds__(256) void k_agg2(const float* __restrict__ h2s,
                                              const float* __restrict__ dinv,
                                              const int* __restrict__ offs,
                                              const int* __restrict__ adj,
                                              const float* __restrict__ b2,
                                              float* __restrict__ out, int n) {
    int i = blockIdx.x * 256 + threadIdx.x;
    if (i >= n) return;
    int s = offs[i], e = offs[i + 1];
    float a0x = 0.f, a0y = 0.f, a1x = 0.f, a1y = 0.f;
    float a2x = 0.f, a2y = 0.f, a3x = 0.f, a3y = 0.f;
    int p = s;
    for (; p + 4 <= e; p += 4) {
        int s0 = adj[p], s1 = adj[p + 1], s2 = adj[p + 2], s3 = adj[p + 3];
        float2 v0 = *(const float2*)(h2s + (size_t)s0 * 2);
        float2 v1 = *(const float2*)(h2s + (size_t)s1 * 2);
        float2 v2 = *(const float2*)(h2s + (size_t)s2 * 2);
        float2 v3 = *(const float2*)(h2s + (size_t)s3 * 2);
        a0x += v0.x; a0y += v0.y;
        a1x += v1.x; a1y += v1.y;
        a2x += v2.x; a2y += v2.y;
        a3x += v3.x; a3y += v3.y;
    }
    int rem = e - p;
    if (rem > 0) {
        int q0 = adj[p];
        int q1 = (rem > 1) ? adj[p + 1] : q0;
        int q2 = (rem > 2) ? adj[p + 2] : q0;
        float2 v0 = *(const float2*)(h2s + (size_t)q0 * 2);
        float2 v1 = *(const float2*)(h2s + (size_t)q1 * 2);
        float2 v2 = *(const float2*)(h2s + (size_t)q2 * 2);
        a0x += v0.x; a0y += v0.y;
        if (rem > 1) { a1x += v1.x; a1y += v1.y; }
        if (rem > 2) { a2x += v2.x; a2y += v2.y; }
    }
    float ax = (a0x + a1x) + (a2x + a3x);
    float ay = (a0y + a1y) + (a2y + a3y);
    float di = dinv[i];
    float2 hv = *(const float2*)(h2s + (size_t)i * 2);
    out[(size_t)i * 2]     = fmaf(di, ax + hv.x, b2[0]);
    out[(size_t)i * 2 + 1] = fmaf(di, ay + hv.y, b2[1]);
}

extern "C" void kernel_launch(void* const* d_in, const int* in_sizes, int n_in,
                              void* d_out, int out_size, void* d_ws, size_t ws_size,
                              hipStream_t stream) {
    const float* x  = (const float*)d_in[0];
    const int*   ei = (const int*)d_in[1];
    const float* W1 = (const float*)d_in[2];
    const float* b1 = (const float*)d_in[3];
    const float* W2 = (const float*)d_in[4];
    const float* b2 = (const float*)d_in[5];
    float* out = (float*)d_out;

    int N = in_sizes[0] / 128;   // 100000
    int E = in_sizes[1] / 2;     // 1600000
    const int* row = ei;
    const int* col = ei + E;

    char* ws = (char*)d_ws;
    size_t off = 0;
    auto alloc = [&](size_t bytes) -> char* {
        char* p = ws + off;
        off = WS_ALIGN(off + bytes);
        return p;
    };
    const int NSB  = 8 * 49;                 // 392 sub-buckets
    int*   bcur   = (int*)alloc(512 + (size_t)NSB * 64);  // bcur (8x16) + bcur2 (392x16)
    int*   bcur2  = bcur + 128;
    int*   deg    = (int*)alloc((size_t)N * 4);
    int*   offs   = (int*)alloc((size_t)(N + 1) * 4);
    int*   bsums  = (int*)alloc(4096);
    float* dinv   = (float*)alloc((size_t)N * 4);
    int*   adj    = (int*)alloc((size_t)E * 4);
    float* h1s    = (float*)alloc((size_t)N * 64 * 4);
    float* h2s    = (float*)alloc((size_t)N * 2 * 4);
    unsigned int* pairs1 = (unsigned int*)alloc((size_t)8 * 262144 * 4);   // 8.4MB
    unsigned int* pairs2 = (unsigned int*)h1s;  // 392*8192*4=12.8MB, dead before gemm1

    int nb   = (N + 1023) / 1024;
    int npg  = (N + 7) / 8;                  // 12500
    const int CAP1 = 262144;                 // per-bucket capacity
    const int CAP2 = 8192;                   // per-sub-bucket capacity
    unsigned int magic = (unsigned int)(((1ULL << 44) + (unsigned long long)npg - 1)
                                        / (unsigned long long)npg);

    hipMemsetAsync(bcur, 0, 512 + (size_t)NSB * 64, stream);
    hipLaunchKernelGGL(k_bucket, dim3((E + 2047) / 2048), dim3(256), 0, stream,
                       row, col, bcur, pairs1, E, magic, npg, CAP1);
    hipLaunchKernelGGL(k_refine, dim3(512), dim3(256), 0, stream,
                       pairs1, bcur, bcur2, pairs2, CAP1, CAP2);
    hipLaunchKernelGGL(k_degcnt, dim3(NSB), dim3(256), 0, stream, pairs2, bcur2, deg, npg, CAP2);
    hipLaunchKernelGGL(k_scan_blocks, dim3(nb), dim3(1024), 0, stream, deg, offs + 1, bsums, N);
    hipLaunchKernelGGL(k_scan_sums, dim3(1), dim3(1024), 0, stream, bsums, nb);
    hipLaunchKernelGGL(k_add_offsets, dim3((N + 255) / 256), dim3(256), 0, stream,
                       offs, bsums, deg, dinv, N);
    hipLaunchKernelGGL(k_binsort, dim3(NSB), dim3(256), 0, stream, pairs2, bcur2, offs, adj, npg, CAP2);
    hipLaunchKernelGGL(k_gemm1, dim3((N + 31) / 32), dim3(256), 0, stream, x, W1, dinv, h1s, N);
    hipLaunchKernelGGL(k_agg1, dim3((N + 3) / 4), dim3(256), 0, stream, h1s, dinv, offs, adj, b1, W2, h2s, N);
    hipLaunchKernelGGL(k_agg2, dim3((N + 255) / 256), dim3(256), 0, stream, h2s, dinv, offs, adj, b2, out, N);
}

// Round 8
// 168.832 us; speedup vs baseline: 1.6627x; 1.0474x over previous
//
#include <hip/hip_runtime.h>
#include <hip/hip_fp16.h>

#define WS_ALIGN(x) (((x) + size_t(255)) & ~size_t(255))

// ---- Phase A: partition edges into 8 col-range buckets. Packed edge:
// row (18b) << 14 | local_col (14b, < 12500). Block-tiled LDS histogram ->
// ONE padded global atomicAdd per bucket per block. No per-edge global atomics.
__global__ __launch_bounds__(256) void k_bucket(const int* __restrict__ row,
                                                const int* __restrict__ col,
                                                int* __restrict__ bcur,   // stride 16 ints
                                                unsigned int* __restrict__ pairs,
                                                int E, unsigned int magic, int npg, int cap) {
    __shared__ int lcnt[4][8];
    __shared__ int wbase[4][8];
    int wid = threadIdx.x >> 6;
    if (threadIdx.x < 32) lcnt[threadIdx.x >> 3][threadIdx.x & 7] = 0;
    __syncthreads();

    int t0 = blockIdx.x * 2048;
    int b[8], rk[8];
    unsigned int pk[8];
#pragma unroll
    for (int k = 0; k < 8; k++) {
        int e = t0 + k * 256 + threadIdx.x;
        b[k] = -1;
        if (e < E) {
            int r = row[e], c = col[e];
            int bb = (int)(((unsigned long long)(unsigned)c * magic) >> 44);  // c/npg
            b[k] = bb;
            pk[k] = ((unsigned)r << 14) | (unsigned)(c - bb * npg);
            rk[k] = atomicAdd(&lcnt[wid][bb], 1);
        }
    }
    __syncthreads();
    if (threadIdx.x < 8) {
        int bb = threadIdx.x;
        int c0 = lcnt[0][bb], c1 = lcnt[1][bb], c2 = lcnt[2][bb], c3 = lcnt[3][bb];
        int tot = (c0 + c1) + (c2 + c3);
        int base = tot ? atomicAdd(&bcur[bb * 16], tot) : 0;
        wbase[0][bb] = base;
        wbase[1][bb] = base + c0;
        wbase[2][bb] = base + c0 + c1;
        wbase[3][bb] = base + c0 + c1 + c2;
    }
    __syncthreads();
#pragma unroll
    for (int k = 0; k < 8; k++) {
        if (b[k] >= 0)
            pairs[(size_t)b[k] * cap + wbase[wid][b[k]] + rk[k]] = pk[k];
    }
}

// ---- Phase B: refine bucket b into 49 sub-buckets of 256 cols (lc>>8).
__global__ __launch_bounds__(256) void k_refine(const unsigned int* __restrict__ pairs1,
                                                const int* __restrict__ bcur,
                                                int* __restrict__ bcur2,  // stride 16 ints
                                                unsigned int* __restrict__ pairs2,
                                                int cap1, int cap2) {
    __shared__ int lcnt[4][64];
    __shared__ int wbase[4][64];
    int b = blockIdx.x & 7;
    int j = blockIdx.x >> 3;
    int nblk = gridDim.x >> 3;
    int wid = threadIdx.x >> 6;
    int cnt = bcur[b * 16];
    const unsigned int* src = pairs1 + (size_t)b * cap1;
    unsigned int* dst = pairs2 + (size_t)b * 49 * cap2;
    int* mycur = bcur2 + b * 49 * 16;

    for (int t0 = j * 4096; t0 < cnt; t0 += nblk * 4096) {
        lcnt[threadIdx.x >> 6][threadIdx.x & 63] = 0;
        __syncthreads();
        unsigned int pk[16];
        int sb[16], rk[16];
#pragma unroll
        for (int k = 0; k < 16; k++) {
            int e = t0 + k * 256 + threadIdx.x;
            sb[k] = -1;
            if (e < cnt) {
                pk[k] = src[e];
                sb[k] = (int)((pk[k] & 16383u) >> 8);   // 0..48
                rk[k] = atomicAdd(&lcnt[wid][sb[k]], 1);
            }
        }
        __syncthreads();
        if (threadIdx.x < 64) {
            int s = threadIdx.x;
            int c0 = lcnt[0][s], c1 = lcnt[1][s], c2 = lcnt[2][s], c3 = lcnt[3][s];
            int tot = (c0 + c1) + (c2 + c3);
            int base = tot ? atomicAdd(&mycur[s * 16], tot) : 0;
            wbase[0][s] = base;
            wbase[1][s] = base + c0;
            wbase[2][s] = base + c0 + c1;
            wbase[3][s] = base + c0 + c1 + c2;
        }
        __syncthreads();
#pragma unroll
        for (int k = 0; k < 16; k++) {
            if (sb[k] >= 0)
                dst[(size_t)sb[k] * cap2 + wbase[wid][sb[k]] + rk[k]] = pk[k];
        }
        __syncthreads();
    }
}

// ---- C1: per-sub-bucket degree count via LDS histogram; coalesced deg store.
__global__ __launch_bounds__(256) void k_degcnt(const unsigned int* __restrict__ pairs2,
                                                const int* __restrict__ bcur2,
                                                int* __restrict__ deg, int npg, int cap2) {
    __shared__ int hist[256];
    int sbid = blockIdx.x;
    int b = sbid / 49, s = sbid - b * 49;
    int cnt = bcur2[sbid * 16];
    const unsigned int* src = pairs2 + (size_t)sbid * cap2;
    hist[threadIdx.x] = 0;
    __syncthreads();
    for (int i = threadIdx.x; i < cnt; i += 256)
        atomicAdd(&hist[src[i] & 255u], 1);
    __syncthreads();
    int ncols = min(256, npg - s * 256);
    if (threadIdx.x < ncols)
        deg[b * npg + s * 256 + threadIdx.x] = hist[threadIdx.x];
}

// per-block inclusive scan of deg -> offs1 (= offsets+1), block totals -> bsums
__global__ __launch_bounds__(1024) void k_scan_blocks(const int* deg, int* offs1, int* bsums, int n) {
    __shared__ int s[1024];
    int gid = blockIdx.x * 1024 + threadIdx.x;
    int v = (gid < n) ? deg[gid] : 0;
    s[threadIdx.x] = v;
    __syncthreads();
    for (int d = 1; d < 1024; d <<= 1) {
        int t = (threadIdx.x >= (unsigned)d) ? s[threadIdx.x - d] : 0;
        __syncthreads();
        s[threadIdx.x] += t;
        __syncthreads();
    }
    if (gid < n) offs1[gid] = s[threadIdx.x];
    if (threadIdx.x == 1023) bsums[blockIdx.x] = s[1023];
}

__global__ __launch_bounds__(1024) void k_scan_sums(int* bsums, int nb) {
    __shared__ int s[1024];
    int v = (threadIdx.x < (unsigned)nb) ? bsums[threadIdx.x] : 0;
    s[threadIdx.x] = v;
    __syncthreads();
    for (int d = 1; d < 1024; d <<= 1) {
        int t = (threadIdx.x >= (unsigned)d) ? s[threadIdx.x - d] : 0;
        __syncthreads();
        s[threadIdx.x] += t;
        __syncthreads();
    }
    if (threadIdx.x < (unsigned)nb) bsums[threadIdx.x] = s[threadIdx.x] - v; // exclusive
}

// finalize offsets; emit dinv. Race-free: thread gid owns offs[gid+1].
__global__ __launch_bounds__(256) void k_add_offsets(int* __restrict__ offs,
                                                     const int* __restrict__ bsums,
                                                     const int* __restrict__ deg,
                                                     float* __restrict__ dinv, int n) {
    int gid = blockIdx.x * 256 + threadIdx.x;
    if (gid >= n) return;
    offs[gid + 1] += bsums[gid >> 10];
    if (gid == 0) offs[0] = 0;
    dinv[gid] = rsqrtf((float)(deg[gid] + 1));  // +1 self loop
}

// ---- C2: per-sub-bucket counting-sort scatter into contiguous adj window.
__global__ __launch_bounds__(256) void k_binsort(const unsigned int* __restrict__ pairs2,
                                                 const int* __restrict__ bcur2,
                                                 const int* __restrict__ offs,
                                                 int* __restrict__ adj, int npg, int cap2) {
    __shared__ int cur[256];
    int sbid = blockIdx.x;
    int b = sbid / 49, s = sbid - b * 49;
    int cnt = bcur2[sbid * 16];
    const unsigned int* src = pairs2 + (size_t)sbid * cap2;
    int colbase = b * npg + s * 256;
    int ncols = min(256, npg - s * 256);
    if (threadIdx.x < ncols) cur[threadIdx.x] = offs[colbase + threadIdx.x];
    __syncthreads();
    for (int i = threadIdx.x; i < cnt; i += 256) {
        unsigned int pk = src[i];
        int pos = atomicAdd(&cur[pk & 255u], 1);
        adj[pos] = (int)(pk >> 14);
    }
}

// h1s = fp16[(x @ W1) * dinv[node]]   x:[n,128] W1:[128,64]
__global__ __launch_bounds__(256) void k_gemm1(const float* __restrict__ x,
                                               const float* __restrict__ W1,
                                               const float* __restrict__ dinv,
                                               __half* __restrict__ h1s, int n) {
    __shared__ float xs[32][132];
    __shared__ float Ws[128][64];
    int base = blockIdx.x * 32;
    for (int q = threadIdx.x; q < 1024; q += 256) {
        int nd = q >> 5, kf = q & 31;
        int gn = base + nd;
        float4 v = (gn < n) ? *(const float4*)&x[(size_t)gn * 128 + kf * 4]
                            : make_float4(0.f, 0.f, 0.f, 0.f);
        *(float4*)&xs[nd][kf * 4] = v;
    }
    for (int q = threadIdx.x; q < 2048; q += 256) {
        float4 v = ((const float4*)W1)[q];
        int k = q >> 4, cf = q & 15;
        *(float4*)&Ws[k][cf * 4] = v;
    }
    __syncthreads();

    int wid = threadIdx.x >> 6, lane = threadIdx.x & 63;
    int r = (wid << 3) + (lane & 7);
    int cbase = (lane >> 3) << 3;
    float4 a0 = make_float4(0.f, 0.f, 0.f, 0.f);
    float4 a1 = make_float4(0.f, 0.f, 0.f, 0.f);
#pragma unroll 4
    for (int k4 = 0; k4 < 32; k4++) {
        float4 xv = *(const float4*)&xs[r][k4 * 4];
#pragma unroll
        for (int kk = 0; kk < 4; kk++) {
            float xk = (&xv.x)[kk];
            float4 w0 = *(const float4*)&Ws[k4 * 4 + kk][cbase];
            float4 w1 = *(const float4*)&Ws[k4 * 4 + kk][cbase + 4];
            a0.x = fmaf(xk, w0.x, a0.x); a0.y = fmaf(xk, w0.y, a0.y);
            a0.z = fmaf(xk, w0.z, a0.z); a0.w = fmaf(xk, w0.w, a0.w);
            a1.x = fmaf(xk, w1.x, a1.x); a1.y = fmaf(xk, w1.y, a1.y);
            a1.z = fmaf(xk, w1.z, a1.z); a1.w = fmaf(xk, w1.w, a1.w);
        }
    }
    int node = base + r;
    if (node < n) {
        float di = dinv[node];
        __half2 h0 = __floats2half2_rn(a0.x * di, a0.y * di);
        __half2 h1 = __floats2half2_rn(a0.z * di, a0.w * di);
        __half2 h2 = __floats2half2_rn(a1.x * di, a1.y * di);
        __half2 h3 = __floats2half2_rn(a1.z * di, a1.w * di);
        __half2* o = (__half2*)&h1s[(size_t)node * 64 + cbase];  // 16B aligned
        o[0] = h0; o[1] = h1; o[2] = h2; o[3] = h3;
    }
}

// layer-1 aggregation (fp16 gathers) fused with layer-2 GEMM (shuffle reduction)
__global__ __launch_bounds__(256) void k_agg1(const __half* __restrict__ h1s,
                                              const float* __restrict__ dinv,
                                              const int* __restrict__ offs,
                                              const int* __restrict__ adj,
                                              const float* __restrict__ b1,
                                              const float* __restrict__ W2,
                                              float* __restrict__ h2s, int n) {
    int wid = threadIdx.x >> 6, lane = threadIdx.x & 63;
    int i = blockIdx.x * 4 + wid;
    if (i >= n) return;
    int s = __builtin_amdgcn_readfirstlane(offs[i]);
    int e = __builtin_amdgcn_readfirstlane(offs[i + 1]);
    float acc0 = 0.f, acc1 = 0.f, acc2 = 0.f, acc3 = 0.f;
    int p = s;
    for (; p + 4 <= e; p += 4) {
        int s0 = adj[p], s1 = adj[p + 1], s2 = adj[p + 2], s3 = adj[p + 3];
        acc0 += __half2float(h1s[(size_t)s0 * 64 + lane]);
        acc1 += __half2float(h1s[(size_t)s1 * 64 + lane]);
        acc2 += __half2float(h1s[(size_t)s2 * 64 + lane]);
        acc3 += __half2float(h1s[(size_t)s3 * 64 + lane]);
    }
    int rem = e - p;
    if (rem > 0) {
        int q0 = adj[p];
        int q1 = (rem > 1) ? adj[p + 1] : q0;
        int q2 = (rem > 2) ? adj[p + 2] : q0;
        float v0 = __half2float(h1s[(size_t)q0 * 64 + lane]);
        float v1 = __half2float(h1s[(size_t)q1 * 64 + lane]);
        float v2 = __half2float(h1s[(size_t)q2 * 64 + lane]);
        acc0 += v0;
        if (rem > 1) acc1 += v1;
        if (rem > 2) acc2 += v2;
    }
    float acc = (acc0 + acc1) + (acc2 + acc3);
    float di = dinv[i];
    float self = __half2float(h1s[(size_t)i * 64 + lane]);
    float val = fmaf(di, acc + self, b1[lane]);
    val = fmaxf(val, 0.f);
    float w0 = W2[lane * 2], w1 = W2[lane * 2 + 1];
    float t0 = val * w0, t1 = val * w1;
#pragma unroll
    for (int m = 1; m < 64; m <<= 1) {
        t0 += __shfl_xor(t0, m, 64);
        t1 += __shfl_xor(t1, m, 64);
    }
    if (lane == 0) {
        h2s[(size_t)i * 2]     = t0 * di;
        h2s[(size_t)i * 2 + 1] = t1 * di;
    }
}

// layer-2 aggregation: thread per node; out = di*(sum h2s[src] + h2s[i]) + b2
__global__ __launch_bounds__(256) void k_agg2(const float* __restrict__ h2s,
                                              const float* __restrict__ dinv,
                                              const int* __restrict__ offs,
                                              const int* __restrict__ adj,
                                              const float* __restrict__ b2,
                                              float* __restrict__ out, int n) {
    int i = blockIdx.x * 256 + threadIdx.x;
    if (i >= n) return;
    int s = offs[i], e = offs[i + 1];
    float a0x = 0.f, a0y = 0.f, a1x = 0.f, a1y = 0.f;
    float a2x = 0.f, a2y = 0.f, a3x = 0.f, a3y = 0.f;
    int p = s;
    for (; p + 4 <= e; p += 4) {
        int s0 = adj[p], s1 = adj[p + 1], s2 = adj[p + 2], s3 = adj[p + 3];
        float2 v0 = *(const float2*)(h2s + (size_t)s0 * 2);
        float2 v1 = *(const float2*)(h2s + (size_t)s1 * 2);
        float2 v2 = *(const float2*)(h2s + (size_t)s2 * 2);
        float2 v3 = *(const float2*)(h2s + (size_t)s3 * 2);
        a0x += v0.x; a0y += v0.y;
        a1x += v1.x; a1y += v1.y;
        a2x += v2.x; a2y += v2.y;
        a3x += v3.x; a3y += v3.y;
    }
    int rem = e - p;
    if (rem > 0) {
        int q0 = adj[p];
        int q1 = (rem > 1) ? adj[p + 1] : q0;
        int q2 = (rem > 2) ? adj[p + 2] : q0;
        float2 v0 = *(const float2*)(h2s + (size_t)q0 * 2);
        float2 v1 = *(const float2*)(h2s + (size_t)q1 * 2);
        float2 v2 = *(const float2*)(h2s + (size_t)q2 * 2);
        a0x += v0.x; a0y += v0.y;
        if (rem > 1) { a1x += v1.x; a1y += v1.y; }
        if (rem > 2) { a2x += v2.x; a2y += v2.y; }
    }
    float ax = (a0x + a1x) + (a2x + a3x);
    float ay = (a0y + a1y) + (a2y + a3y);
    float di = dinv[i];
    float2 hv = *(const float2*)(h2s + (size_t)i * 2);
    out[(size_t)i * 2]     = fmaf(di, ax + hv.x, b2[0]);
    out[(size_t)i * 2 + 1] = fmaf(di, ay + hv.y, b2[1]);
}

extern "C" void kernel_launch(void* const* d_in, const int* in_sizes, int n_in,
                              void* d_out, int out_size, void* d_ws, size_t ws_size,
                              hipStream_t stream) {
    const float* x  = (const float*)d_in[0];
    const int*   ei = (const int*)d_in[1];
    const float* W1 = (const float*)d_in[2];
    const float* b1 = (const float*)d_in[3];
    const float* W2 = (const float*)d_in[4];
    const float* b2 = (const float*)d_in[5];
    float* out = (float*)d_out;

    int N = in_sizes[0] / 128;   // 100000
    int E = in_sizes[1] / 2;     // 1600000
    const int* row = ei;
    const int* col = ei + E;

    char* ws = (char*)d_ws;
    size_t off = 0;
    auto alloc = [&](size_t bytes) -> char* {
        char* p = ws + off;
        off = WS_ALIGN(off + bytes);
        return p;
    };
    const int NSB  = 8 * 49;                 // 392 sub-buckets
    int*   bcur   = (int*)alloc(512 + (size_t)NSB * 64);  // bcur (8x16) + bcur2 (392x16)
    int*   bcur2  = bcur + 128;
    int*   deg    = (int*)alloc((size_t)N * 4);
    int*   offs   = (int*)alloc((size_t)(N + 1) * 4);
    int*   bsums  = (int*)alloc(4096);
    float* dinv   = (float*)alloc((size_t)N * 4);
    int*   adj    = (int*)alloc((size_t)E * 4);
    char*  hbuf   = alloc((size_t)392 * 8192 * 4);        // max(h1s 12.8MB, pairs2 12.8MB)
    __half* h1s   = (__half*)hbuf;
    unsigned int* pairs2 = (unsigned int*)hbuf;           // dead before gemm1 writes h1s
    float* h2s    = (float*)alloc((size_t)N * 2 * 4);
    unsigned int* pairs1 = (unsigned int*)alloc((size_t)8 * 262144 * 4);   // 8.4MB

    int nb   = (N + 1023) / 1024;
    int npg  = (N + 7) / 8;                  // 12500
    const int CAP1 = 262144;                 // per-bucket capacity
    const int CAP2 = 8192;                   // per-sub-bucket capacity
    unsigned int magic = (unsigned int)(((1ULL << 44) + (unsigned long long)npg - 1)
                                        / (unsigned long long)npg);

    hipMemsetAsync(bcur, 0, 512 + (size_t)NSB * 64, stream);
    hipLaunchKernelGGL(k_bucket, dim3((E + 2047) / 2048), dim3(256), 0, stream,
                       row, col, bcur, pairs1, E, magic, npg, CAP1);
    hipLaunchKernelGGL(k_refine, dim3(512), dim3(256), 0, stream,
                       pairs1, bcur, bcur2, pairs2, CAP1, CAP2);
    hipLaunchKernelGGL(k_degcnt, dim3(NSB), dim3(256), 0, stream, pairs2, bcur2, deg, npg, CAP2);
    hipLaunchKernelGGL(k_scan_blocks, dim3(nb), dim3(1024), 0, stream, deg, offs + 1, bsums, N);
    hipLaunchKernelGGL(k_scan_sums, dim3(1), dim3(1024), 0, stream, bsums, nb);
    hipLaunchKernelGGL(k_add_offsets, dim3((N + 255) / 256), dim3(256), 0, stream,
                       offs, bsums, deg, dinv, N);
    hipLaunchKernelGGL(k_binsort, dim3(NSB), dim3(256), 0, stream, pairs2, bcur2, offs, adj, npg, CAP2);
    hipLaunchKernelGGL(k_gemm1, dim3((N + 31) / 32), dim3(256), 0, stream, x, W1, dinv, h1s, N);
    hipLaunchKernelGGL(k_agg1, dim3((N + 3) / 4), dim3(256), 0, stream, h1s, dinv, offs, adj, b1, W2, h2s, N);
    hipLaunchKernelGGL(k_agg2, dim3((N + 255) / 256), dim3(256), 0, stream, h2s, dinv, offs, adj, b2, out, N);
}